// Round 1
// baseline (69.847 us; speedup 1.0000x reference)
//
#include <hip/hip_runtime.h>

// Problem constants (reference: B=128, K=2048, D=512, c=1.0)
#define B_SZ 128
#define K_SZ 2048
#define D_SZ 512

typedef __attribute__((ext_vector_type(8))) short short8;   // 8 bf16 (MFMA A/B frag)
typedef __attribute__((ext_vector_type(4))) float floatx4;  // MFMA acc

// Manual RNE fp32 -> bf16.
static __device__ inline unsigned short f2b(float f) {
  unsigned int u = __float_as_uint(f);
  return (unsigned short)((u + 0x7fffu + ((u >> 16) & 1u)) >> 16);
}

static __device__ inline ushort4 cvt4(float4 v) {
  ushort4 c;
  c.x = f2b(v.x); c.y = f2b(v.y); c.z = f2b(v.z); c.w = f2b(v.w);
  return c;
}

// ---------------------------------------------------------------------------
// Kernel 1 (prep): ONE wave per row. Converts fp32 rows -> linear bf16 images
// in the workspace (done ONCE, vs 128x for x / 4x for p,a in the old fused
// kernel) and computes per-row stats:
//   stats[0..127]        vv[b]  = ||x_b||^2
//   stats[128..2175]     uu[k]  = ||p_k||^2
//   stats[2176..4223]    nua[k] = <u_k, a_k> = -<p_k, a_k>
//   stats[4224..6271]    an[k]  = ||a_k||
// Per lane: 2 float4 loads per array (perfectly coalesced 1KB/instr), two 8B
// bf16 stores per array, 6-level shfl_xor full-wave reduce.
__global__ __launch_bounds__(256) void prep_kernel(
    const float* __restrict__ x, const float* __restrict__ p,
    const float* __restrict__ a, unsigned short* __restrict__ xb,
    unsigned short* __restrict__ pb, unsigned short* __restrict__ ab,
    float* __restrict__ stats) {
  const int wid = (blockIdx.x << 2) + (threadIdx.x >> 6);  // 0..2175
  const int lane = threadIdx.x & 63;
  if (wid < K_SZ) {  // p/a row
    const float4* sp = (const float4*)(p + (size_t)wid * D_SZ);
    const float4* sa = (const float4*)(a + (size_t)wid * D_SZ);
    float4 p0 = sp[lane], p1 = sp[lane + 64];
    float4 a0 = sa[lane], a1 = sa[lane + 64];
    float pp = p0.x * p0.x + p0.y * p0.y + p0.z * p0.z + p0.w * p0.w +
               p1.x * p1.x + p1.y * p1.y + p1.z * p1.z + p1.w * p1.w;
    float pa = p0.x * a0.x + p0.y * a0.y + p0.z * a0.z + p0.w * a0.w +
               p1.x * a1.x + p1.y * a1.y + p1.z * a1.z + p1.w * a1.w;
    float aa = a0.x * a0.x + a0.y * a0.y + a0.z * a0.z + a0.w * a0.w +
               a1.x * a1.x + a1.y * a1.y + a1.z * a1.z + a1.w * a1.w;
    unsigned short* pr = pb + (size_t)wid * D_SZ;
    unsigned short* ar = ab + (size_t)wid * D_SZ;
    *(ushort4*)(pr + lane * 4) = cvt4(p0);
    *(ushort4*)(pr + 256 + lane * 4) = cvt4(p1);
    *(ushort4*)(ar + lane * 4) = cvt4(a0);
    *(ushort4*)(ar + 256 + lane * 4) = cvt4(a1);
#pragma unroll
    for (int off = 32; off; off >>= 1) {
      pp += __shfl_xor(pp, off, 64);
      pa += __shfl_xor(pa, off, 64);
      aa += __shfl_xor(aa, off, 64);
    }
    if (lane == 0) {
      stats[B_SZ + wid] = pp;                    // uu
      stats[B_SZ + K_SZ + wid] = -pa;            // nua
      stats[B_SZ + 2 * K_SZ + wid] = sqrtf(aa);  // an
    }
  } else {  // x row
    const int b = wid - K_SZ;  // 0..127
    const float4* sx = (const float4*)(x + (size_t)b * D_SZ);
    float4 v0 = sx[lane], v1 = sx[lane + 64];
    float vv = v0.x * v0.x + v0.y * v0.y + v0.z * v0.z + v0.w * v0.w +
               v1.x * v1.x + v1.y * v1.y + v1.z * v1.z + v1.w * v1.w;
    unsigned short* xr = xb + (size_t)b * D_SZ;
    *(ushort4*)(xr + lane * 4) = cvt4(v0);
    *(ushort4*)(xr + 256 + lane * 4) = cvt4(v1);
#pragma unroll
    for (int off = 32; off; off >>= 1) vv += __shfl_xor(vv, off, 64);
    if (lane == 0) stats[b] = vv;
  }
}

// ---------------------------------------------------------------------------
// Kernel 2 (main): dual bf16 MFMA GEMM (<x,p>, <x,a>) + fused hyperbolic-MLR
// epilogue. NO LDS staging: MFMA fragments are loaded straight from the bf16
// workspace images (16B/lane, 16B-aligned, L2/L3-resident after prep), so the
// only barrier is the d-half partial combine (8KB LDS).
// Block = 32 b x 16 k tile. Grid = 4 x 128 = 512 blocks. 4 waves: wave w ->
// m-half (w&1), d-half (w>>1); 8 k-steps x 2 MFMAs each.
// blockIdx mapping: kt = blk & 127 -> the 4 m-blocks of one k-tile differ by
// 128 ≡ 0 (mod 8) -> same XCD -> shared p/a tile stays in that XCD's L2.
// Fragment layouts (m89/m91-verified):
//   A/B: row = lane&15, d = (lane>>4)*8 + j  (16B/lane, row-major == B^T)
//   C/D: n = lane&15, m = (lane>>4)*4 + reg
__global__ __launch_bounds__(256, 2) void mlr_kernel(
    const unsigned short* __restrict__ xb, const unsigned short* __restrict__ pb,
    const unsigned short* __restrict__ ab, const float* __restrict__ stats,
    float* __restrict__ out) {
  __shared__ float part[2048];  // part_s[1024] | part_a[1024] = 8 KB
  const int t = threadIdx.x;
  const int mt = blockIdx.x >> 7;   // 0..3
  const int kt = blockIdx.x & 127;  // 0..127
  const int w = t >> 6, lane = t & 63;
  const int row16 = lane & 15, quad = lane >> 4;
  const int wm = w & 1, dh = w >> 1;

  const unsigned short* xrow =
      xb + (size_t)(mt * 32 + wm * 16 + row16) * D_SZ + dh * 256 + quad * 8;
  const unsigned short* prow =
      pb + (size_t)(kt * 16 + row16) * D_SZ + dh * 256 + quad * 8;
  const unsigned short* arow =
      ab + (size_t)(kt * 16 + row16) * D_SZ + dh * 256 + quad * 8;

  // Hoist epilogue stat loads above the MFMA loop (independent; latency
  // overlaps fragment loads + MFMA instead of sitting in the tail).
  const int bm = mt * 32, kn = kt * 16;
  float vvb[2], uuk[2], nuak[2], ank[2];
#pragma unroll
  for (int o = 0; o < 2; ++o) {
    const int idx = t + o * 256;
    const int m16 = idx >> 4, n = idx & 15;
    vvb[o] = stats[bm + m16];
    uuk[o] = stats[B_SZ + kn + n];
    nuak[o] = stats[B_SZ + K_SZ + kn + n];
    ank[o] = stats[B_SZ + 2 * K_SZ + kn + n];
  }

  floatx4 cs = {0.f, 0.f, 0.f, 0.f};
  floatx4 ca = {0.f, 0.f, 0.f, 0.f};
#pragma unroll
  for (int dc = 0; dc < 8; ++dc) {
    short8 af = *(const short8*)(xrow + dc * 32);
    short8 bp = *(const short8*)(prow + dc * 32);
    short8 bv = *(const short8*)(arow + dc * 32);
    cs = __builtin_amdgcn_mfma_f32_16x16x32_bf16(af, bp, cs, 0, 0, 0);
    ca = __builtin_amdgcn_mfma_f32_16x16x32_bf16(af, bv, ca, 0, 0, 0);
  }

  // Combine d-halves through LDS (single barrier in the whole kernel).
  float* part_s = part;
  float* part_a = part + 1024;
  *(floatx4*)&part_s[t * 4] = cs;  // t == w*64 + lane
  *(floatx4*)&part_a[t * 4] = ca;
  __syncthreads();

  // Epilogue: 2 outputs per thread (c = 1).
#pragma unroll
  for (int o = 0; o < 2; ++o) {
    const int idx = t + o * 256;   // 0..511 -> (m16, n)
    const int m16 = idx >> 4;      // local b
    const int n = idx & 15;        // local k
    const int wmI = m16 >> 4, mr = m16 & 15;
    const int lsrc = ((mr >> 2) << 4) | n;
    const int reg = mr & 3;
    const float sdot = part_s[(wmI * 64 + lsrc) * 4 + reg] +
                       part_s[((2 + wmI) * 64 + lsrc) * 4 + reg];
    const float adot = part_a[(wmI * 64 + lsrc) * 4 + reg] +
                       part_a[((2 + wmI) * 64 + lsrc) * 4 + reg];
    const float beta = 1.f - uuk[o];            // 1 - c*||p||^2
    const float scale = (2.f / beta) * ank[o];  // lam_p * ||a||
    const float uv = -sdot;                     // <u,x> = -<p,x>
    const float alpha = 1.f + 2.f * uv + vvb[o];
    const float den = 1.f + 2.f * uv + uuk[o] * vvb[o];
    const float inv = 1.f / den;
    const float wwn = (alpha * alpha * uuk[o] + 2.f * alpha * beta * uv +
                       beta * beta * vvb[o]) * inv * inv;
    const float wa = (alpha * nuak[o] + beta * adot) * inv;
    const float z = 2.f * wa / (ank[o] * (1.f - wwn));
    out[(size_t)(bm + m16) * K_SZ + (kn + n)] = scale * asinhf(z);
  }
}

extern "C" void kernel_launch(void* const* d_in, const int* in_sizes, int n_in,
                              void* d_out, int out_size, void* d_ws, size_t ws_size,
                              hipStream_t stream) {
  const float* x = (const float*)d_in[0];  // inp [B,D]
  const float* p = (const float*)d_in[1];  // p   [K,D]
  const float* a = (const float*)d_in[2];  // a   [K,D]
  float* out = (float*)d_out;              // [B,K] fp32

  // Workspace layout (4.15 MiB used; ws is 256 MiB):
  //   xb [128][512] bf16 | pb [2048][512] bf16 | ab [2048][512] bf16 |
  //   stats: vv[128] | uu[2048] | nua[2048] | an[2048] fp32
  unsigned short* xb = (unsigned short*)d_ws;
  unsigned short* pb = xb + (size_t)B_SZ * D_SZ;
  unsigned short* ab = pb + (size_t)K_SZ * D_SZ;
  float* stats = (float*)(ab + (size_t)K_SZ * D_SZ);

  prep_kernel<<<(K_SZ + B_SZ) / 4, 256, 0, stream>>>(x, p, a, xb, pb, ab, stats);
  mlr_kernel<<<(B_SZ / 32) * (K_SZ / 16), 256, 0, stream>>>(xb, pb, ab, stats, out);
}

// Round 2
// 66.664 us; speedup vs baseline: 1.0477x; 1.0477x over previous
//
#include <hip/hip_runtime.h>

// Problem constants (reference: B=128, K=2048, D=512, c=1.0)
#define B_SZ 128
#define K_SZ 2048
#define D_SZ 512
#define ROWP 520  // padded LDS row stride in bf16 (1040 B = 65 x 16B chunks,
                  // 65 % 8 == 1 -> 16 rows cycle all 8 bank-quads: b128
                  // fragment reads are perfectly bank-balanced)

typedef __attribute__((ext_vector_type(8))) short short8;   // 8 bf16
typedef __attribute__((ext_vector_type(4))) float floatx4;  // MFMA acc

// fp32 -> bf16 RNE via compiler-native fptrunc. LLVM fptrunc f32->bf16 is
// round-to-nearest-even (same as the old manual +0x7fff trick -> bit-identical
// results), and hipcc vectorizes adjacent casts into v_cvt_pk_bf16_f32
// (0.5 inst/elem vs 3 inst/elem manual) — per learn_hip m240, scalar casts
// beat hand-written cvt_pk inline asm because the compiler schedules them.
static __device__ inline unsigned short f2b(float f) {
  __bf16 h = (__bf16)f;
  return __builtin_bit_cast(unsigned short, h);
}

// ONE fused kernel: stage x/p/a tiles fp32->bf16 into LDS while computing
// per-row stats (vv, uu, nua, an) in fp32, then dual bf16-MFMA GEMM
// (<x,p>, <x,a>), partial-combine through LDS, fused hyperbolic-MLR epilogue.
// Block = 32 b x 16 k. Grid = 4 x 128 = 512 blocks = 2/CU (LDS 65.3 KB caps
// at exactly 2). 256 threads = 4 waves: wave w -> m-half (w&1), d-half (w>>1),
// each wave does 8 k-steps x 2 MFMAs on a 16x16 tile.
// blockIdx mapping: kt = blk & 127 -> the 4 m-blocks of one k-tile differ by
// 128 ≡ 0 (mod 8) -> same XCD -> p/a rows hit that XCD's L2 after first touch.
// Fragment layouts (m89/m91-verified):
//   A/B: row = lane&15, d = (lane>>4)*8 + j (16B/lane, row-major == B^T)
//   C/D: n = lane&15, m = (lane>>4)*4 + reg
//
// Rationale for single-kernel (R1 post-mortem): the bench window carries a
// fixed ~63 µs harness constant (256 MiB workspace poison fill ~40.6 µs +
// ~20 µs of reset memset dispatch overhead). Kernel-side work is ~4 µs, so
// dispatch count matters more than staging redundancy — one kernel, minimal
// VALU.
__global__ __launch_bounds__(256, 2) void fused_kernel(
    const float* __restrict__ x, const float* __restrict__ p,
    const float* __restrict__ a, float* __restrict__ out) {
  __shared__ unsigned short xs[32 * ROWP];   // 33280 B
  __shared__ unsigned short ps[16 * ROWP];   // 16640 B (partials alias here)
  __shared__ unsigned short as_[16 * ROWP];  // 16640 B
  __shared__ float stats[32 + 48];           // vv[32] | uu[16] | nua[16] | an[16]

  const int t = threadIdx.x;
  const int bm = (blockIdx.x >> 7) * 32;   // 4 m-tiles of 32 b
  const int kn = (blockIdx.x & 127) * 16;  // 128 k-tiles of 16 k

  // ---- Phase 0a: stage x (32 rows), vv stats. 8 threads/row, 16 float4 ea.
  {
    const int r = t >> 3, s = t & 7;
    const float4* src = (const float4*)(x + (size_t)(bm + r) * D_SZ);
    float vvp = 0.f;
#pragma unroll
    for (int i = 0; i < 16; ++i) {
      float4 v = src[s + i * 8];
      vvp += v.x * v.x + v.y * v.y + v.z * v.z + v.w * v.w;
      ushort4 c;
      c.x = f2b(v.x); c.y = f2b(v.y); c.z = f2b(v.z); c.w = f2b(v.w);
      *(ushort4*)&xs[r * ROWP + (s + i * 8) * 4] = c;
    }
    vvp += __shfl_xor(vvp, 1, 64);
    vvp += __shfl_xor(vvp, 2, 64);
    vvp += __shfl_xor(vvp, 4, 64);
    if (s == 0) stats[r] = vvp;
  }

  // ---- Phase 0b: stage p,a (16 rows), uu/nua/an stats. 16 thr/row, 8 f4 ea.
  {
    const int r = t >> 4, s = t & 15;
    const float4* sp = (const float4*)(p + (size_t)(kn + r) * D_SZ);
    const float4* sa = (const float4*)(a + (size_t)(kn + r) * D_SZ);
    float pp = 0.f, pa = 0.f, aa = 0.f;
#pragma unroll
    for (int i = 0; i < 8; ++i) {
      float4 pv = sp[s + i * 16];
      float4 av = sa[s + i * 16];
      pp += pv.x * pv.x + pv.y * pv.y + pv.z * pv.z + pv.w * pv.w;
      pa += pv.x * av.x + pv.y * av.y + pv.z * av.z + pv.w * av.w;
      aa += av.x * av.x + av.y * av.y + av.z * av.z + av.w * av.w;
      ushort4 pc, ac;
      pc.x = f2b(pv.x); pc.y = f2b(pv.y); pc.z = f2b(pv.z); pc.w = f2b(pv.w);
      ac.x = f2b(av.x); ac.y = f2b(av.y); ac.z = f2b(av.z); ac.w = f2b(av.w);
      *(ushort4*)&ps[r * ROWP + (s + i * 16) * 4] = pc;
      *(ushort4*)&as_[r * ROWP + (s + i * 16) * 4] = ac;
    }
    pp += __shfl_xor(pp, 1, 64);
    pa += __shfl_xor(pa, 1, 64);
    aa += __shfl_xor(aa, 1, 64);
    pp += __shfl_xor(pp, 2, 64);
    pa += __shfl_xor(pa, 2, 64);
    aa += __shfl_xor(aa, 2, 64);
    pp += __shfl_xor(pp, 4, 64);
    pa += __shfl_xor(pa, 4, 64);
    aa += __shfl_xor(aa, 4, 64);
    pp += __shfl_xor(pp, 8, 64);
    pa += __shfl_xor(pa, 8, 64);
    aa += __shfl_xor(aa, 8, 64);
    if (s == 0) {
      stats[32 + r] = pp;        // uu
      stats[48 + r] = -pa;       // nua
      stats[64 + r] = sqrtf(aa); // an
    }
  }
  __syncthreads();

  // ---- Phase 1: dual MFMA. wave w: m-half wm = w&1, d-half dh = w>>1.
  const int w = t >> 6, lane = t & 63;
  const int row16 = lane & 15, quad = lane >> 4;
  const int wm = w & 1, dh = w >> 1;
  const unsigned short* xrow = &xs[(wm * 16 + row16) * ROWP + dh * 256 + quad * 8];
  const unsigned short* prow = &ps[row16 * ROWP + dh * 256 + quad * 8];
  const unsigned short* arow = &as_[row16 * ROWP + dh * 256 + quad * 8];
  floatx4 cs = {0.f, 0.f, 0.f, 0.f};
  floatx4 ca = {0.f, 0.f, 0.f, 0.f};
#pragma unroll
  for (int dc = 0; dc < 8; ++dc) {
    short8 af = *(const short8*)(xrow + dc * 32);
    short8 bp = *(const short8*)(prow + dc * 32);
    short8 bv = *(const short8*)(arow + dc * 32);
    cs = __builtin_amdgcn_mfma_f32_16x16x32_bf16(af, bp, cs, 0, 0, 0);
    ca = __builtin_amdgcn_mfma_f32_16x16x32_bf16(af, bv, ca, 0, 0, 0);
  }

  // ---- Phase 2: combine d-halves through LDS (alias ps; done reading it).
  __syncthreads();
  float* part_s = (float*)ps;          // [4 waves][64 lanes][4 regs] = 4 KB
  float* part_a = part_s + 1024;       // 4 KB
  *(floatx4*)&part_s[(w * 64 + lane) * 4] = cs;
  *(floatx4*)&part_a[(w * 64 + lane) * 4] = ca;
  __syncthreads();

  // ---- Phase 3: epilogue, 2 outputs per thread (c = 1).
#pragma unroll
  for (int o = 0; o < 2; ++o) {
    const int idx = t + o * 256;   // 0..511 -> (m16, n)
    const int m16 = idx >> 4;      // 0..31 local b
    const int n = idx & 15;        // local k
    const int wmI = m16 >> 4, mr = m16 & 15;
    const int lsrc = ((mr >> 2) << 4) | n;
    const int reg = mr & 3;
    const float sdot = part_s[(wmI * 64 + lsrc) * 4 + reg] +
                       part_s[((2 + wmI) * 64 + lsrc) * 4 + reg];
    const float adot = part_a[(wmI * 64 + lsrc) * 4 + reg] +
                       part_a[((2 + wmI) * 64 + lsrc) * 4 + reg];
    const float vvb = stats[m16];
    const float uuk = stats[32 + n];
    const float nuak = stats[48 + n];
    const float ank = stats[64 + n];
    const float beta = 1.f - uuk;            // 1 - c*||p||^2
    const float scale = (2.f / beta) * ank;  // lam_p * ||a||
    const float uv = -sdot;                  // <u,x> = -<p,x>
    const float alpha = 1.f + 2.f * uv + vvb;
    const float den = 1.f + 2.f * uv + uuk * vvb;
    const float inv = 1.f / den;
    const float wwn =
        (alpha * alpha * uuk + 2.f * alpha * beta * uv + beta * beta * vvb) *
        inv * inv;
    const float wa = (alpha * nuak + beta * adot) * inv;
    const float z = 2.f * wa / (ank * (1.f - wwn));
    out[(size_t)(bm + m16) * K_SZ + (kn + n)] = scale * asinhf(z);
  }
}

extern "C" void kernel_launch(void* const* d_in, const int* in_sizes, int n_in,
                              void* d_out, int out_size, void* d_ws, size_t ws_size,
                              hipStream_t stream) {
  const float* x = (const float*)d_in[0];  // inp [B,D]
  const float* p = (const float*)d_in[1];  // p   [K,D]
  const float* a = (const float*)d_in[2];  // a   [K,D]
  float* out = (float*)d_out;              // [B,K] fp32
  (void)d_ws; (void)ws_size;               // no workspace needed

  fused_kernel<<<(B_SZ / 32) * (K_SZ / 16), 256, 0, stream>>>(x, p, a, out);
}